// Round 8
// baseline (162.171 us; speedup 1.0000x reference)
//
#include <hip/hip_runtime.h>
#include <stdint.h>

// Problem constants
constexpr int CXR = 15, ECG = 14, EHR = 13;
constexpr int TOTAL = 42;
constexpr int MPITCH = 44;          // f32 fused-matrix row pitch (fuse1 output)
constexpr float LN_EPS = 1e-5f;

// Workspace layout (float offsets)
constexpr int WS_M    = 0;                    // A_eff f32, 42 x 44
constexpr int WS_B    = TOTAL * MPITCH;       // 1848 fused bias (42)
constexpr int WS_G    = WS_B + TOTAL;         // ln gamma (42)
constexpr int WS_BETA = WS_G + TOTAL;         // ln beta  (42)
constexpr int WS_FRAG = 1976;                 // W' fp16 A-frags (16B aligned)

// Tiling: 64 rows per wave-tile, 1 wave per block, persistent grid
constexpr int WROWS = 64;
constexpr int S0F = 0, S1F = WROWS * CXR, S2F = S1F + WROWS * ECG; // 0,960,1856
constexpr int WC0 = WROWS * CXR / 4, WC1 = WROWS * ECG / 4, WC2 = WROWS * EHR / 4;
constexpr int STAGE_B = WROWS * TOTAL * 4;    // 10752 B stage buffer
constexpr int WORK_B  = WROWS * TOTAL * 4;    // 10752 B fp16-tile / compact-out
constexpr int ARENA_B = STAGE_B + WORK_B;     // 21504 B -> 7 blocks/CU

constexpr int GRID_BLOCKS = 1792;             // 7 x 256 CUs, fully resident

typedef _Float16 half8 __attribute__((ext_vector_type(8)));
typedef float float4v __attribute__((ext_vector_type(4)));

struct FuseArgs {
    const float *in_w, *in_b, *out_w, *out_b, *kv_w, *kv_b, *ln_g, *ln_b;
    int E, R;
};

// fuse1: A_eff = out_w @ Wv @ kv_w (E x 42), b_eff, ln params -> ws (f32)
__global__ void fuse_weights_kernel(FuseArgs a0, FuseArgs a1, FuseArgs a2,
                                    float* __restrict__ ws) {
    FuseArgs a = (blockIdx.x == 0) ? a0 : (blockIdx.x == 1 ? a1 : a2);
    const int E = a.E, R = a.R;
    const int tid = threadIdx.x;

    __shared__ float T1[15 * 42];
    __shared__ float b1[15];

    for (int idx = tid; idx < E * TOTAL; idx += blockDim.x) {
        int i = idx / TOTAL, j = idx % TOTAL;
        float acc = 0.f;
        for (int k = 0; k < E; ++k)
            acc = fmaf(a.in_w[(2 * E + i) * E + k], a.kv_w[k * TOTAL + j], acc);
        T1[i * TOTAL + j] = acc;
    }
    if (tid < E) {
        float acc = a.in_b[2 * E + tid];
        for (int k = 0; k < E; ++k)
            acc = fmaf(a.in_w[(2 * E + tid) * E + k], a.kv_b[k], acc);
        b1[tid] = acc;
    }
    __syncthreads();

    for (int idx = tid; idx < E * MPITCH; idx += blockDim.x) {
        int i = idx / MPITCH, j = idx % MPITCH;
        float acc = 0.f;
        if (j < TOTAL)
            for (int k = 0; k < E; ++k)
                acc = fmaf(a.out_w[i * E + k], T1[k * TOTAL + j], acc);
        ws[WS_M + (R + i) * MPITCH + j] = acc;
    }
    if (tid < E) {
        float acc = a.out_b[tid];
        for (int k = 0; k < E; ++k)
            acc = fmaf(a.out_w[tid * E + k], b1[k], acc);
        ws[WS_B + R + tid]    = acc;
        ws[WS_G + R + tid]    = a.ln_g[tid];
        ws[WS_BETA + R + tid] = a.ln_b[tid];
    }
}

// fuse2: W' fp16 A-frags, MFMA lane order. M = out-features, segment m padded
// to 16 rows (pad rows ZERO -> y=0 there, LN pad algebra uses that).
// A-frag: lane&15 = M-row within m-tile; k = t*32 + 8*(lane>>4) + i.
// W'[fo][k] = A_eff[glob][k] + (k==glob) identity; k==42 -> b_eff; else 0.
__global__ void fuse_frags_kernel(float* __restrict__ ws) {
    const int tid = threadIdx.x;
    if (tid >= 384) return;
    const int l = tid & 63, nt = tid >> 6;   // nt = m*2 + t
    const int m = nt >> 1, t = nt & 1;
    const int j = l & 15;
    const int k0 = t * 32 + 8 * (l >> 4);
    const int offm = (m == 0) ? 0 : (m == 1 ? CXR : CXR + ECG);
    const int Em   = (m == 0) ? CXR : (m == 1 ? ECG : EHR);
    half8 h;
#pragma unroll
    for (int i = 0; i < 8; ++i) {
        int k = k0 + i;
        float v = 0.f;
        if (j < Em) {
            int glob = offm + j;
            if (k < TOTAL) {
                v = ws[WS_M + glob * MPITCH + k];
                if (k == glob) v += 1.f;          // residual identity
            } else if (k == TOTAL) {
                v = ws[WS_B + glob];              // bias via x[42]=1.0
            }
        }
        h[i] = (_Float16)v;
    }
    ((half8*)(ws + WS_FRAG))[nt * 64 + l] = h;
}

// Async global->LDS staging (linear, width 16). Always issues ceil(CH/64)=4
// instructions (partial lanes masked) -> 12 vmcnt increments per tile.
template <int CH>
__device__ __forceinline__ void stage_seg(const float* __restrict__ g,
                                          float* lds_seg_base, int lane) {
#pragma unroll
    for (int it = 0; it < (CH + 63) / 64; ++it) {
        int idx = lane + it * 64;
        if (idx < CH) {
            const __attribute__((address_space(1))) void* src =
                (const __attribute__((address_space(1))) void*)
                    ((const char*)g + (size_t)idx * 16);
            __attribute__((address_space(3))) void* dst =
                (__attribute__((address_space(3))) void*)
                    ((char*)lds_seg_base + it * 1024);
            __builtin_amdgcn_global_load_lds(src, dst, 16, 0, 0);
        }
    }
}

__global__ __launch_bounds__(64) void cmca_main(
        const float* __restrict__ cxr, const float* __restrict__ ecg,
        const float* __restrict__ ehr, const float* __restrict__ ws,
        float* __restrict__ out_cxr, float* __restrict__ out_ecg,
        float* __restrict__ out_ehr, int NT) {
    __shared__ __align__(16) char arena[ARENA_B];
    float* stg = (float*)arena;                 // f32 stage (DMA target)
    char*  fb  = arena + STAGE_B;               // fp16 X-tile (work area)
    float* wk  = (float*)(arena + STAGE_B);     // compact f32 out (work area)

    const int lane = threadIdx.x;
    const int h = lane >> 4, b15 = lane & 15;

    // ---- per-wave constants (once) ----
    const half8* fr = (const half8*)(ws + WS_FRAG);
    half8 wf[3][2];
#pragma unroll
    for (int m = 0; m < 3; ++m)
#pragma unroll
        for (int t = 0; t < 2; ++t) wf[m][t] = fr[(m * 2 + t) * 64 + lane];

    constexpr int Earr[3]  = {CXR, ECG, EHR};
    constexpr int OFFa[3]  = {0, CXR, CXR + ECG};
    float gg[3][4], bb[3][4];
#pragma unroll
    for (int m = 0; m < 3; ++m)
#pragma unroll
        for (int r = 0; r < 4; ++r) {
            int j = 4 * h + r;
            bool v = j < Earr[m];
            gg[m][r] = v ? ws[WS_G + OFFa[m] + j] : 0.f;
            bb[m][r] = v ? ws[WS_BETA + OFFa[m] + j] : 0.f;
        }

    // ---- prologue: stage first tile ----
    const int t0 = blockIdx.x;
    stage_seg<WC0>(cxr + (size_t)t0 * (WROWS * CXR), stg + S0F, lane);
    stage_seg<WC1>(ecg + (size_t)t0 * (WROWS * ECG), stg + S1F, lane);
    stage_seg<WC2>(ehr + (size_t)t0 * (WROWS * EHR), stg + S2F, lane);
    asm volatile("s_waitcnt vmcnt(0)" ::: "memory");

    for (int t = t0; t < NT; t += GRID_BLOCKS) {
        // ---- gather this lane's row (f32) from stage ----
        float x[TOTAL];
#pragma unroll
        for (int j = 0; j < CXR; ++j) x[j] = stg[S0F + lane * CXR + j];
#pragma unroll
        for (int j = 0; j < ECG; ++j) x[CXR + j] = stg[S1F + lane * ECG + j];
#pragma unroll
        for (int j = 0; j < EHR; ++j) x[CXR + ECG + j] = stg[S2F + lane * EHR + j];
        // gather must complete before DMA overwrites stage
        asm volatile("s_waitcnt lgkmcnt(0)" ::: "memory");
        __builtin_amdgcn_sched_barrier(0);

        // ---- prefetch next tile into the just-freed stage buffer ----
        const int tn = t + GRID_BLOCKS;
        const bool more = tn < NT;
        if (more) {
            stage_seg<WC0>(cxr + (size_t)tn * (WROWS * CXR), stg + S0F, lane);
            stage_seg<WC1>(ecg + (size_t)tn * (WROWS * ECG), stg + S1F, lane);
            stage_seg<WC2>(ehr + (size_t)tn * (WROWS * EHR), stg + S2F, lane);
        }

        // ---- write fp16 X row (k: 0-41 = x, 42 = 1.0, 43-63 = 0), swizzled ----
        const int swz = (lane & 7) << 4;
#pragma unroll
        for (int j = 0; j < 6; ++j) {
            half8 h8;
#pragma unroll
            for (int e = 0; e < 8; ++e) {
                int k = j * 8 + e;
                float v = (k < TOTAL) ? x[k] : (k == TOTAL ? 1.f : 0.f);
                h8[e] = (_Float16)v;
            }
            *(half8*)(fb + lane * 128 + ((j * 16) ^ swz)) = h8;
        }
        *(float4v*)(fb + lane * 128 + (96 ^ swz))  = float4v{0.f, 0.f, 0.f, 0.f};
        *(float4v*)(fb + lane * 128 + (112 ^ swz)) = float4v{0.f, 0.f, 0.f, 0.f};

        // ---- read B-frags (X^T): lane&15 = batch col, k by (h, t2) ----
        half8 xf[4][2];
#pragma unroll
        for (int n = 0; n < 4; ++n) {
            int row = n * 16 + b15;
            int rsw = (row & 7) << 4;
#pragma unroll
            for (int t2 = 0; t2 < 2; ++t2)
                xf[n][t2] = *(const half8*)(fb + row * 128 +
                                            ((t2 * 64 + h * 16) ^ rsw));
        }

        // ---- 24 MFMAs: Y^T[48 x 64] = W'[48 x 64k] * X^T[64k x 64] ----
        float4v acc[3][4];
#pragma unroll
        for (int m = 0; m < 3; ++m)
#pragma unroll
            for (int n = 0; n < 4; ++n) acc[m][n] = float4v{0.f, 0.f, 0.f, 0.f};
#pragma unroll
        for (int t2 = 0; t2 < 2; ++t2)
#pragma unroll
            for (int m = 0; m < 3; ++m)
#pragma unroll
                for (int n = 0; n < 4; ++n)
                    acc[m][n] = __builtin_amdgcn_mfma_f32_16x16x32_f16(
                        wf[m][t2], xf[n][t2], acc[m][n], 0, 0, 0);

        // ---- in-register LN per (batch col, segment); scatter compact ----
        // lane holds: batch b = n*16+b15; features f = 4h+r of segment m.
        // Pad features are exactly 0 (zero W' rows) -> sum unaffected,
        // var fix: subtract PAD*mu^2.
#pragma unroll
        for (int n = 0; n < 4; ++n) {
            int brow = n * 16 + b15;
#pragma unroll
            for (int m = 0; m < 3; ++m) {
                constexpr int SEGF[3] = {S0F, S1F, S2F};
                const int E = Earr[m];
                const float invE = 1.0f / E;
                const float PAD = (float)(16 - E);
                float s = acc[m][n][0] + acc[m][n][1] + acc[m][n][2] + acc[m][n][3];
                s += __shfl_xor(s, 16, 64);
                s += __shfl_xor(s, 32, 64);
                float mu = s * invE;
                float q = 0.f;
#pragma unroll
                for (int r = 0; r < 4; ++r) {
                    float d = acc[m][n][r] - mu;
                    q = fmaf(d, d, q);
                }
                q += __shfl_xor(q, 16, 64);
                q += __shfl_xor(q, 32, 64);
                float var = (q - PAD * mu * mu) * invE;
                float rs = rsqrtf(var + LN_EPS);
#pragma unroll
                for (int r = 0; r < 4; ++r) {
                    int j = 4 * h + r;
                    if (j < E) {
                        float nv = (acc[m][n][r] - mu) * rs;
                        wk[SEGF[m] + brow * E + j] = fmaf(nv, gg[m][r], bb[m][r]);
                    }
                }
            }
        }

        // ---- coalesced float4 stores from compact area (12 issues) ----
        const float4v* w4 = (const float4v*)wk;
        float4v* o0 = (float4v*)(out_cxr + (size_t)t * (WROWS * CXR));
        float4v* o1 = (float4v*)(out_ecg + (size_t)t * (WROWS * ECG));
        float4v* o2 = (float4v*)(out_ehr + (size_t)t * (WROWS * EHR));
#pragma unroll
        for (int it = 0; it < 4; ++it) {
            int idx = lane + it * 64;
            if (idx < WC0) o0[idx] = w4[idx];
        }
#pragma unroll
        for (int it = 0; it < 4; ++it) {
            int idx = lane + it * 64;
            if (idx < WC1) o1[idx] = w4[WC0 + idx];
        }
#pragma unroll
        for (int it = 0; it < 4; ++it) {
            int idx = lane + it * 64;
            if (idx < WC2) o2[idx] = w4[WC0 + WC1 + idx];
        }

        // ---- counted wait: 12 youngest (this tile's stores) may stay in
        // flight; everything older (incl. the 12 DMA loads) has retired.
        if (more) {
            asm volatile("s_waitcnt vmcnt(12)" ::: "memory");
            __builtin_amdgcn_sched_barrier(0);
        }
    }
}

extern "C" void kernel_launch(void* const* d_in, const int* in_sizes, int n_in,
                              void* d_out, int out_size, void* d_ws, size_t ws_size,
                              hipStream_t stream) {
    const float* cxr = (const float*)d_in[0];
    const float* ecg = (const float*)d_in[1];
    const float* ehr = (const float*)d_in[2];
    float* ws = (float*)d_ws;
    float* out = (float*)d_out;

    const size_t Bn = (size_t)in_sizes[0] / CXR;   // 2097152

    auto mk = [&](int base, int E, int R) {
        FuseArgs a;
        a.in_w  = (const float*)d_in[base + 0];
        a.in_b  = (const float*)d_in[base + 1];
        a.out_w = (const float*)d_in[base + 2];
        a.out_b = (const float*)d_in[base + 3];
        a.kv_w  = (const float*)d_in[base + 4];
        a.kv_b  = (const float*)d_in[base + 5];
        a.ln_g  = (const float*)d_in[base + 6];
        a.ln_b  = (const float*)d_in[base + 7];
        a.E = E; a.R = R;
        return a;
    };
    FuseArgs a0 = mk(3, CXR, 0);
    FuseArgs a1 = mk(11, ECG, CXR);
    FuseArgs a2 = mk(19, EHR, CXR + ECG);

    fuse_weights_kernel<<<3, 256, 0, stream>>>(a0, a1, a2, ws);
    fuse_frags_kernel<<<1, 384, 0, stream>>>(ws);

    const int NT = (int)(Bn / WROWS);              // 32768 tiles
    cmca_main<<<GRID_BLOCKS, 64, 0, stream>>>(cxr, ecg, ehr, ws,
                                              out,
                                              out + Bn * CXR,
                                              out + Bn * (CXR + ECG), NT);
}